// Round 4
// baseline (195.777 us; speedup 1.0000x reference)
//
#include <hip/hip_runtime.h>
#include <hip/hip_bf16.h>
#include <stdint.h>

#define NROWS 16384
#define NDIM  1024
#define NLAB  64
#define NC    65
#define CPAD  80

typedef float float4v __attribute__((ext_vector_type(4)));
typedef short short8  __attribute__((ext_vector_type(8)));

// ---- workspace layout (bytes) ----
static constexpr size_t CNT_B   = 0;        // 80 u32 counts
static constexpr size_t ACT_B   = 320;      // 8 u32 active bitfields
static constexpr size_t SCALE_B = 352;      // 80 f32 (w/||abf_c||)
static constexpr size_t WSUM_B  = 672;      // 1 f32 loss accumulator
static constexpr size_t ZERO_BYTES = 676;   // memset range
static constexpr size_t MASK_B  = 1024;     // 16384 u64 row bitmasks
static constexpr size_t ABF_B   = 132096;   // 80*1024 bf16 unit anchors
static constexpr size_t LABT_B  = 295936;   // 80*16384 bf16 lab^T (A-operand)
static constexpr size_t PART_B  = 2917376;  // kslices*80*1024 f32 partials
static constexpr size_t XBF_B   = 13403136; // 16384*1024 bf16 x copy
static constexpr size_t XBF_END = XBF_B + (size_t)NROWS * NDIM * 2;  // 46957568

__device__ __forceinline__ unsigned short bf16u(float f) {
    __hip_bfloat16 h = __float2bfloat16(f);
    return __builtin_bit_cast(unsigned short, h);
}
__device__ __forceinline__ unsigned pk2(float a, float b) {
    return (unsigned)bf16u(a) | ((unsigned)bf16u(b) << 16);
}

// ---- K1: label bitmasks + counts + labT (bf16 0/1 matrix, c-major) ----
__global__ __launch_bounds__(256) void k1_labels(const int* __restrict__ label,
                                                 unsigned long long* __restrict__ masks,
                                                 unsigned* __restrict__ counts,
                                                 unsigned short* __restrict__ labT) {
    __shared__ unsigned cnt[NC];
    __shared__ unsigned long long smask[64];
    int t = threadIdx.x;
    if (t < NC) cnt[t] = 0;
    __syncthreads();
    int wave = t >> 6, lane = t & 63;
    int rowblock = blockIdx.x * 64;
    unsigned creg = 0, zreg = 0;
#pragma unroll 4
    for (int p = 0; p < 16; ++p) {
        int row = rowblock + p * 4 + wave;
        int v = label[row * NLAB + lane];
        unsigned long long m = __ballot(v != 0);
        creg += (unsigned)((m >> lane) & 1ull);
        if (lane == 0) {
            masks[row] = m;
            smask[p * 4 + wave] = m;
            zreg += (m == 0ull) ? 1u : 0u;
        }
    }
    atomicAdd(&cnt[lane], creg);
    if (lane == 0 && zreg) atomicAdd(&cnt[64], zreg);
    __syncthreads();
    if (t < NC) atomicAdd(&counts[t], cnt[t]);
    // labT[c][row] for this 64-row block: bf16{0,1} packed 2/u32
    for (int job = t; job < CPAD * 32; job += 256) {
        int c = job >> 5, rp = job & 31;
        unsigned long long m0 = smask[rp * 2], m1 = smask[rp * 2 + 1];
        unsigned b0, b1;
        if (c < 64)      { b0 = (unsigned)((m0 >> c) & 1ull); b1 = (unsigned)((m1 >> c) & 1ull); }
        else if (c == 64){ b0 = (m0 == 0ull); b1 = (m1 == 0ull); }
        else             { b0 = 0u; b1 = 0u; }
        unsigned pk = (b0 ? 0x3F80u : 0u) | (b1 ? 0x3F800000u : 0u);
        *(unsigned*)(labT + (size_t)c * NROWS + rowblock + rp * 2) = pk;
    }
}

// ---- K2: sums = labT @ x via bf16 MFMA, software-pipelined; also emits xbf ----
__global__ __launch_bounds__(256) void k2_sums(const float* __restrict__ x,
                                               const unsigned short* __restrict__ labT,
                                               float* __restrict__ partial,
                                               unsigned short* __restrict__ xbf,
                                               int kslices, int writexbf) {
    __shared__ unsigned short xT[64][40];   // [d][32 rows + 8 pad]
    int t = threadIdx.x, wave = t >> 6, lane = t & 63;
    int q = lane >> 4, col = lane & 15;
    int dg = blockIdx.x & 15, ks = blockIdx.x >> 4;
    int rowsper = NROWS / kslices;
    int row0 = ks * rowsper;
    int d0 = dg * 64;
    int sd = t & 63, rblk = t >> 6;

    float4v acc[5];
#pragma unroll
    for (int ct = 0; ct < 5; ++ct) acc[ct] = (float4v){0.f, 0.f, 0.f, 0.f};

    int steps = rowsper >> 5;
    float v[8];
#pragma unroll
    for (int j = 0; j < 8; ++j)
        v[j] = x[(size_t)(row0 + rblk * 8 + j) * NDIM + d0 + sd];

    for (int step = 0; step < steps; ++step) {
        int rbase = row0 + step * 32;
        __syncthreads();                    // prior frag reads done
        uint4 w;
        w.x = pk2(v[0], v[1]); w.y = pk2(v[2], v[3]);
        w.z = pk2(v[4], v[5]); w.w = pk2(v[6], v[7]);
        *(uint4*)&xT[sd][rblk * 8] = w;
        __syncthreads();
        float vn[8];
        if (step + 1 < steps) {
#pragma unroll
            for (int j = 0; j < 8; ++j)     // prefetch next tile (overlaps MFMA phase)
                vn[j] = x[(size_t)(rbase + 32 + rblk * 8 + j) * NDIM + d0 + sd];
        } else {
#pragma unroll
            for (int j = 0; j < 8; ++j) vn[j] = 0.f;
        }
        if (writexbf) {
#pragma unroll
            for (int j = 0; j < 8; ++j)
                xbf[(size_t)(rbase + rblk * 8 + j) * NDIM + d0 + sd] = bf16u(v[j]);
        }
        int4 braw = *(const int4*)&xT[wave * 16 + col][q * 8];
        short8 bf = __builtin_bit_cast(short8, braw);
#pragma unroll
        for (int ct = 0; ct < 5; ++ct) {
            int4 araw = *(const int4*)(labT + (size_t)(ct * 16 + col) * NROWS + rbase + q * 8);
            short8 af = __builtin_bit_cast(short8, araw);
            acc[ct] = __builtin_amdgcn_mfma_f32_16x16x32_bf16(af, bf, acc[ct], 0, 0, 0);
        }
#pragma unroll
        for (int j = 0; j < 8; ++j) v[j] = vn[j];
    }
    float* pb = partial + (size_t)ks * CPAD * NDIM;
#pragma unroll
    for (int ct = 0; ct < 5; ++ct)
#pragma unroll
        for (int reg = 0; reg < 4; ++reg)
            pb[(size_t)(ct * 16 + q * 4 + reg) * NDIM + d0 + wave * 16 + col] = acc[ct][reg];
}

// ---- K2b: reduce partials, normalize anchors -> bf16, per-c scale, active bits ----
__global__ __launch_bounds__(256) void k2b_norm(const float* __restrict__ wptr,
                                                const unsigned* __restrict__ counts,
                                                const float* __restrict__ partial,
                                                int kslices,
                                                unsigned short* __restrict__ abf,
                                                float* __restrict__ scale,
                                                unsigned* __restrict__ act) {
    int c = blockIdx.x, t = threadIdx.x;
    if (c >= NC) {
        *(uint2*)(abf + (size_t)c * NDIM + t * 4) = make_uint2(0u, 0u);
        if (t == 0) scale[c] = 0.f;
        return;
    }
    int d0 = t * 4;
    float4 s = make_float4(0.f, 0.f, 0.f, 0.f);
#pragma unroll 4
    for (int sl = 0; sl < kslices; ++sl) {
        float4 p = *(const float4*)(partial + (size_t)sl * CPAD * NDIM + (size_t)c * NDIM + d0);
        s.x += p.x; s.y += p.y; s.z += p.z; s.w += p.w;
    }
    unsigned cnt = counts[c];
    float invc = 1.0f / (float)(cnt > 0u ? cnt : 1u);
    float ax = s.x * invc, ay = s.y * invc, az = s.z * invc, aw = s.w * invc;
    float ss = ax * ax + ay * ay + az * az + aw * aw;

    __shared__ float red[8];
#pragma unroll
    for (int m = 32; m >= 1; m >>= 1) ss += __shfl_xor(ss, m, 64);
    if ((t & 63) == 0) red[t >> 6] = ss;
    __syncthreads();
    ss = red[0] + red[1] + red[2] + red[3];

    float denom = fmaxf(sqrtf(ss), 1e-8f);
    float rinv = invc / denom;

    unsigned short h0 = bf16u(s.x * rinv), h1 = bf16u(s.y * rinv);
    unsigned short h2 = bf16u(s.z * rinv), h3 = bf16u(s.w * rinv);
    *(uint2*)(abf + (size_t)c * NDIM + d0) =
        make_uint2(((unsigned)h1 << 16) | h0, ((unsigned)h3 << 16) | h2);

    float f0 = __bfloat162float(__builtin_bit_cast(__hip_bfloat16, h0));
    float f1 = __bfloat162float(__builtin_bit_cast(__hip_bfloat16, h1));
    float f2 = __bfloat162float(__builtin_bit_cast(__hip_bfloat16, h2));
    float f3 = __bfloat162float(__builtin_bit_cast(__hip_bfloat16, h3));
    float nb2 = f0 * f0 + f1 * f1 + f2 * f2 + f3 * f3;
#pragma unroll
    for (int m = 32; m >= 1; m >>= 1) nb2 += __shfl_xor(nb2, m, 64);
    if ((t & 63) == 0) red[4 + (t >> 6)] = nb2;
    __syncthreads();
    if (t == 0) {
        float n2 = red[4] + red[5] + red[6] + red[7];
        scale[c] = (n2 > 0.f) ? (wptr[0] / sqrtf(n2)) : 0.f;
        if (cnt > 0u) atomicOr(&act[c >> 4], 1u << (c & 15));
    }
}

// ---- K3 (fast): barrier-free K-loop. A-frags direct from xbf; k-split x4/block ----
__global__ __launch_bounds__(256, 4) void k3_loss(const unsigned short* __restrict__ xbf,
                                                  const unsigned short* __restrict__ abf,
                                                  const unsigned long long* __restrict__ masks,
                                                  const unsigned* __restrict__ act,
                                                  const float* __restrict__ scale,
                                                  const float* __restrict__ bptr,
                                                  float* __restrict__ wsum) {
    __shared__ float xch[3][64 * 21];
    int t = threadIdx.x, kh = t >> 6, lane = t & 63;
    int q = lane >> 4, col = lane & 15;
    int rowbase = blockIdx.x * 16;

    const unsigned short* arow = xbf + (size_t)(rowbase + col) * NDIM + kh * 256 + q * 8;
    const unsigned short* bbase = abf + (size_t)col * NDIM + kh * 256 + q * 8;

    float4v acc[5];
#pragma unroll
    for (int ct = 0; ct < 5; ++ct) acc[ct] = (float4v){0.f, 0.f, 0.f, 0.f};
    float sq = 0.f;

#pragma unroll 4
    for (int step = 0; step < 8; ++step) {
        int k0 = step * 32;
        int4 araw = *(const int4*)(arow + k0);
        uint4 au = __builtin_bit_cast(uint4, araw);
        float f;
        f = __builtin_bit_cast(float, au.x << 16);          sq = fmaf(f, f, sq);
        f = __builtin_bit_cast(float, au.x & 0xFFFF0000u);  sq = fmaf(f, f, sq);
        f = __builtin_bit_cast(float, au.y << 16);          sq = fmaf(f, f, sq);
        f = __builtin_bit_cast(float, au.y & 0xFFFF0000u);  sq = fmaf(f, f, sq);
        f = __builtin_bit_cast(float, au.z << 16);          sq = fmaf(f, f, sq);
        f = __builtin_bit_cast(float, au.z & 0xFFFF0000u);  sq = fmaf(f, f, sq);
        f = __builtin_bit_cast(float, au.w << 16);          sq = fmaf(f, f, sq);
        f = __builtin_bit_cast(float, au.w & 0xFFFF0000u);  sq = fmaf(f, f, sq);
        short8 af = __builtin_bit_cast(short8, araw);
#pragma unroll
        for (int ct = 0; ct < 5; ++ct) {
            int4 braw = *(const int4*)(bbase + (size_t)ct * 16 * NDIM + k0);
            short8 bf = __builtin_bit_cast(short8, braw);
            acc[ct] = __builtin_amdgcn_mfma_f32_16x16x32_bf16(af, bf, acc[ct], 0, 0, 0);
        }
    }
    sq += __shfl_xor(sq, 16, 64);
    sq += __shfl_xor(sq, 32, 64);   // lane: quarter-norm^2 of row rowbase+(lane&15)

    if (kh) {
        float* dst = &xch[kh - 1][lane * 21];
#pragma unroll
        for (int ct = 0; ct < 5; ++ct)
#pragma unroll
            for (int r = 0; r < 4; ++r) dst[ct * 4 + r] = acc[ct][r];
        dst[20] = sq;
    }
    __syncthreads();
    if (kh) return;
#pragma unroll
    for (int j = 0; j < 3; ++j) {
        const float* src = &xch[j][lane * 21];
#pragma unroll
        for (int ct = 0; ct < 5; ++ct)
#pragma unroll
            for (int r = 0; r < 4; ++r) acc[ct][r] += src[ct * 4 + r];
        sq += src[20];
    }

    float bv = bptr[0];
    float sc[5]; unsigned ab[5];
#pragma unroll
    for (int ct = 0; ct < 5; ++ct) { sc[ct] = scale[ct * 16 + col]; ab[ct] = act[ct]; }

    float contrib = 0.f;
#pragma unroll
    for (int reg = 0; reg < 4; ++reg) {
        int rl = q * 4 + reg;
        int row = rowbase + rl;
        float xn2 = __shfl(sq, (lane & 48) | rl, 64);
        float inv = 1.0f / fmaxf(sqrtf(xn2), 1e-8f);
        unsigned long long mask = masks[row];
        float v[5]; float lmax = -1e30f;
#pragma unroll
        for (int ct = 0; ct < 5; ++ct) {
            float lg = acc[ct][reg] * sc[ct] * inv + bv;   // w*cos + b
            bool a = (ab[ct] >> col) & 1u;
            v[ct] = a ? lg : -1e30f;
            lmax = fmaxf(lmax, v[ct]);
        }
#pragma unroll
        for (int m = 1; m < 16; m <<= 1) lmax = fmaxf(lmax, __shfl_xor(lmax, m, 16));
        float es = 0.f;
#pragma unroll
        for (int ct = 0; ct < 5; ++ct) es += expf(v[ct] - lmax);
#pragma unroll
        for (int m = 1; m < 16; m <<= 1) es += __shfl_xor(es, m, 16);
        float lse = lmax + logf(es);
        float ps = 0.f;
#pragma unroll
        for (int ct = 0; ct < 5; ++ct) {
            int c = ct * 16 + col;
            bool pos = (c < 64) ? (((mask >> c) & 1ull) != 0ull)
                                : ((c == 64) ? (mask == 0ull) : false);
            ps += pos ? v[ct] : 0.f;
        }
#pragma unroll
        for (int m = 1; m < 16; m <<= 1) ps += __shfl_xor(ps, m, 16);
        float npos = mask ? (float)__popcll(mask) : 1.0f;
        float crow = ps - npos * lse;
        if (col == 0) contrib += crow;
    }
#pragma unroll
    for (int m = 1; m < 64; m <<= 1) contrib += __shfl_xor(contrib, m, 64);
    if (lane == 0) atomicAdd(wsum, contrib);
}

// ---- K3 (fallback, ws too small for xbf): round-3 LDS-staged version ----
__global__ __launch_bounds__(256) void k3_loss_lds(const float* __restrict__ x,
                                                   const unsigned short* __restrict__ abf,
                                                   const unsigned long long* __restrict__ masks,
                                                   const unsigned* __restrict__ act,
                                                   const float* __restrict__ scale,
                                                   const float* __restrict__ bptr,
                                                   float* __restrict__ wsum) {
    __shared__ unsigned short xs[32][72];
    __shared__ float xn2[32];
    __shared__ float xch[2][64 * 20];
    int t = threadIdx.x, wave = t >> 6, lane = t & 63;
    int q = lane >> 4, col = lane & 15;
    int p = wave >> 1, kh = wave & 1;
    int blockrow0 = blockIdx.x * 32;
    int rowbase = blockrow0 + p * 16;
    int srow = t >> 3, skoff = (t & 7) * 8;

    float4v acc[5];
#pragma unroll
    for (int ct = 0; ct < 5; ++ct) acc[ct] = (float4v){0.f, 0.f, 0.f, 0.f};
    float sq = 0.f;
    const float* xsrc = x + (size_t)(blockrow0 + srow) * NDIM + skoff;

    for (int step = 0; step < 16; ++step) {
        int k0 = step * 64;
        float4 f0 = *(const float4*)(xsrc + k0);
        float4 f1 = *(const float4*)(xsrc + k0 + 4);
        __syncthreads();
        sq += f0.x * f0.x + f0.y * f0.y + f0.z * f0.z + f0.w * f0.w
            + f1.x * f1.x + f1.y * f1.y + f1.z * f1.z + f1.w * f1.w;
        uint4 w;
        w.x = pk2(f0.x, f0.y); w.y = pk2(f0.z, f0.w);
        w.z = pk2(f1.x, f1.y); w.w = pk2(f1.z, f1.w);
        *(uint4*)&xs[srow][skoff] = w;
        __syncthreads();
        int kk = kh * 32 + q * 8;
        int4 araw = *(const int4*)&xs[p * 16 + col][kk];
        short8 af = __builtin_bit_cast(short8, araw);
#pragma unroll
        for (int ct = 0; ct < 5; ++ct) {
            int4 braw = *(const int4*)(abf + (size_t)(ct * 16 + col) * NDIM + k0 + kk);
            short8 bf = __builtin_bit_cast(short8, braw);
            acc[ct] = __builtin_amdgcn_mfma_f32_16x16x32_bf16(af, bf, acc[ct], 0, 0, 0);
        }
    }
#pragma unroll
    for (int m = 1; m < 8; m <<= 1) sq += __shfl_xor(sq, m, 8);
    if ((t & 7) == 0) xn2[srow] = sq;
    if (kh == 1) {
        float* dst = &xch[p][lane * 20];
#pragma unroll
        for (int ct = 0; ct < 5; ++ct)
#pragma unroll
            for (int r = 0; r < 4; ++r) dst[ct * 4 + r] = acc[ct][r];
    }
    __syncthreads();
    if (kh == 1) return;
    {
        const float* src = &xch[p][lane * 20];
#pragma unroll
        for (int ct = 0; ct < 5; ++ct)
#pragma unroll
            for (int r = 0; r < 4; ++r) acc[ct][r] += src[ct * 4 + r];
    }
    float bv = bptr[0];
    float sc[5]; unsigned ab[5];
#pragma unroll
    for (int ct = 0; ct < 5; ++ct) { sc[ct] = scale[ct * 16 + col]; ab[ct] = act[ct]; }
    float contrib = 0.f;
#pragma unroll
    for (int reg = 0; reg < 4; ++reg) {
        int rl = q * 4 + reg;
        int row = rowbase + rl;
        float inv = 1.0f / fmaxf(sqrtf(xn2[p * 16 + rl]), 1e-8f);
        unsigned long long mask = masks[row];
        float v[5]; float lmax = -1e30f;
#pragma unroll
        for (int ct = 0; ct < 5; ++ct) {
            float lg = acc[ct][reg] * sc[ct] * inv + bv;
            bool a = (ab[ct] >> col) & 1u;
            v[ct] = a ? lg : -1e30f;
            lmax = fmaxf(lmax, v[ct]);
        }
#pragma unroll
        for (int m = 1; m < 16; m <<= 1) lmax = fmaxf(lmax, __shfl_xor(lmax, m, 16));
        float es = 0.f;
#pragma unroll
        for (int ct = 0; ct < 5; ++ct) es += expf(v[ct] - lmax);
#pragma unroll
        for (int m = 1; m < 16; m <<= 1) es += __shfl_xor(es, m, 16);
        float lse = lmax + logf(es);
        float ps = 0.f;
#pragma unroll
        for (int ct = 0; ct < 5; ++ct) {
            int c = ct * 16 + col;
            bool pos = (c < 64) ? (((mask >> c) & 1ull) != 0ull)
                                : ((c == 64) ? (mask == 0ull) : false);
            ps += pos ? v[ct] : 0.f;
        }
#pragma unroll
        for (int m = 1; m < 16; m <<= 1) ps += __shfl_xor(ps, m, 16);
        float npos = mask ? (float)__popcll(mask) : 1.0f;
        float crow = ps - npos * lse;
        if (col == 0) contrib += crow;
    }
#pragma unroll
    for (int m = 1; m < 64; m <<= 1) contrib += __shfl_xor(contrib, m, 64);
    if (lane == 0) atomicAdd(wsum, contrib);
}

// ---- K4: loss = -sum(logp over positive pairs) / n_pairs ----
__global__ void k4_final(const unsigned* __restrict__ counts,
                         const float* __restrict__ wsum,
                         float* __restrict__ out) {
    if (threadIdx.x == 0 && blockIdx.x == 0) {
        float np = 0.f;
        for (int c = 0; c < NC; ++c) np += (float)counts[c];
        out[0] = -wsum[0] / np;
    }
}

extern "C" void kernel_launch(void* const* d_in, const int* in_sizes, int n_in,
                              void* d_out, int out_size, void* d_ws, size_t ws_size,
                              hipStream_t stream) {
    (void)in_sizes; (void)n_in; (void)out_size;
    const float* x = (const float*)d_in[0];
    const int* label = (const int*)d_in[1];
    const float* w = (const float*)d_in[2];
    const float* b = (const float*)d_in[3];

    char* ws = (char*)d_ws;
    unsigned* counts = (unsigned*)(ws + CNT_B);
    unsigned* act = (unsigned*)(ws + ACT_B);
    float* scale = (float*)(ws + SCALE_B);
    float* wsum = (float*)(ws + WSUM_B);
    unsigned long long* masks = (unsigned long long*)(ws + MASK_B);
    unsigned short* abf = (unsigned short*)(ws + ABF_B);
    unsigned short* labT = (unsigned short*)(ws + LABT_B);
    float* partial = (float*)(ws + PART_B);
    unsigned short* xbf = (unsigned short*)(ws + XBF_B);

    int use_xbf = (ws_size >= XBF_END) ? 1 : 0;
    int kslices = 32;
    size_t cap = use_xbf ? XBF_B : ws_size;
    while (kslices > 8 && PART_B + (size_t)kslices * CPAD * NDIM * 4 > cap) kslices >>= 1;

    hipMemsetAsync(d_ws, 0, ZERO_BYTES, stream);
    hipLaunchKernelGGL(k1_labels, dim3(256), dim3(256), 0, stream, label, masks, counts, labT);
    hipLaunchKernelGGL(k2_sums, dim3(16 * kslices), dim3(256), 0, stream,
                       x, labT, partial, xbf, kslices, use_xbf);
    hipLaunchKernelGGL(k2b_norm, dim3(CPAD), dim3(256), 0, stream,
                       w, counts, partial, kslices, abf, scale, act);
    if (use_xbf) {
        hipLaunchKernelGGL(k3_loss, dim3(NROWS / 16), dim3(256), 0, stream,
                           xbf, abf, masks, act, scale, b, wsum);
    } else {
        hipLaunchKernelGGL(k3_loss_lds, dim3(NROWS / 32), dim3(256), 0, stream,
                           x, abf, masks, act, scale, b, wsum);
    }
    hipLaunchKernelGGL(k4_final, dim3(1), dim3(64), 0, stream, counts, wsum, (float*)d_out);
}

// Round 5
// 192.853 us; speedup vs baseline: 1.0152x; 1.0152x over previous
//
#include <hip/hip_runtime.h>
#include <hip/hip_bf16.h>
#include <stdint.h>

#define NROWS 16384
#define NDIM  1024
#define NLAB  64
#define NC    65
#define CPAD  80

typedef float float4v __attribute__((ext_vector_type(4)));
typedef short short8  __attribute__((ext_vector_type(8)));

// ---- workspace layout (bytes) ----
static constexpr size_t CNT_B   = 0;        // 80 u32 counts
static constexpr size_t ACT_B   = 320;      // 8 u32 active bitfields
static constexpr size_t SCALE_B = 352;      // 80 f32 (w/||abf_c||)
static constexpr size_t WSUM_B  = 672;      // 1 f32 loss accumulator
static constexpr size_t NORM2_B = 704;      // 80 f32 ||anchor||^2 accumulators
static constexpr size_t ZERO_BYTES = 1024;  // memset range
static constexpr size_t MASK_B  = 1024;     // 16384 u64 row bitmasks
static constexpr size_t ABF_B   = 132096;   // 80*1024 bf16 unit anchors
static constexpr size_t LABT_B  = 295936;   // 80*16384 bf16 lab^T (A-operand)
static constexpr size_t AF32_B  = 2917376;  // 80*1024 f32 mean anchors
static constexpr size_t PART_B  = 3245056;  // kslices*80*1024 f32 partials
static constexpr size_t SLAB    = (size_t)CPAD * NDIM * 4;

__device__ __forceinline__ unsigned short bf16u(float f) {
    __hip_bfloat16 h = __float2bfloat16(f);
    return __builtin_bit_cast(unsigned short, h);
}
__device__ __forceinline__ short bf16s(float f) {
    __hip_bfloat16 h = __float2bfloat16(f);
    return __builtin_bit_cast(short, h);
}

// ---- K1: label bitmasks + counts + labT (bf16 0/1 matrix, c-major) ----
__global__ __launch_bounds__(256) void k1_labels(const int* __restrict__ label,
                                                 unsigned long long* __restrict__ masks,
                                                 unsigned* __restrict__ counts,
                                                 unsigned short* __restrict__ labT) {
    __shared__ unsigned cnt[NC];
    __shared__ unsigned long long smask[64];
    int t = threadIdx.x;
    if (t < NC) cnt[t] = 0;
    __syncthreads();
    int wave = t >> 6, lane = t & 63;
    int rowblock = blockIdx.x * 64;
    unsigned creg = 0, zreg = 0;
#pragma unroll 4
    for (int p = 0; p < 16; ++p) {
        int row = rowblock + p * 4 + wave;
        int v = label[row * NLAB + lane];
        unsigned long long m = __ballot(v != 0);
        creg += (unsigned)((m >> lane) & 1ull);
        if (lane == 0) {
            masks[row] = m;
            smask[p * 4 + wave] = m;
            zreg += (m == 0ull) ? 1u : 0u;
        }
    }
    atomicAdd(&cnt[lane], creg);
    if (lane == 0 && zreg) atomicAdd(&cnt[64], zreg);
    __syncthreads();
    if (t < NC) atomicAdd(&counts[t], cnt[t]);
    for (int job = t; job < CPAD * 32; job += 256) {
        int c = job >> 5, rp = job & 31;
        unsigned long long m0 = smask[rp * 2], m1 = smask[rp * 2 + 1];
        unsigned b0, b1;
        if (c < 64)      { b0 = (unsigned)((m0 >> c) & 1ull); b1 = (unsigned)((m1 >> c) & 1ull); }
        else if (c == 64){ b0 = (m0 == 0ull); b1 = (m1 == 0ull); }
        else             { b0 = 0u; b1 = 0u; }
        unsigned pk = (b0 ? 0x3F80u : 0u) | (b1 ? 0x3F800000u : 0u);
        *(unsigned*)(labT + (size_t)c * NROWS + rowblock + rp * 2) = pk;
    }
}

// ---- K2: sums = labT @ x, barrier-free. B-frags straight from fp32 x with
// depth-2 register prefetch; A from L2-hot labT. wave = 16-d tile x 5 ctiles. ----
__global__ __launch_bounds__(256) void k2_sums(const float* __restrict__ x,
                                               const unsigned short* __restrict__ labT,
                                               float* __restrict__ partial,
                                               int kslices) {
    int t = threadIdx.x, wave = t >> 6, lane = t & 63;
    int q = lane >> 4, col = lane & 15;
    int dg = blockIdx.x & 15, ks = blockIdx.x >> 4;
    int rowsper = NROWS / kslices;
    int row0 = ks * rowsper;
    int d = dg * 64 + wave * 16 + col;        // this thread's output dim
    int steps = rowsper >> 5;                 // 32 rows per step

    const float* bp = x + (size_t)(row0 + q * 8) * NDIM + d;
    const size_t rstep = (size_t)32 * NDIM;

    float4v acc[5];
#pragma unroll
    for (int ct = 0; ct < 5; ++ct) acc[ct] = (float4v){0.f, 0.f, 0.f, 0.f};

    float v0[8], v1[8], vt[8];
#pragma unroll
    for (int j = 0; j < 8; ++j) v0[j] = bp[(size_t)j * NDIM];
#pragma unroll
    for (int j = 0; j < 8; ++j) v1[j] = bp[rstep + (size_t)j * NDIM];

    for (int s = 0; s < steps; ++s) {
        if (s + 2 < steps) {
            const float* np = bp + (size_t)(s + 2) * rstep;
#pragma unroll
            for (int j = 0; j < 8; ++j) vt[j] = np[(size_t)j * NDIM];
        }
        short8 bfv;
#pragma unroll
        for (int j = 0; j < 8; ++j) bfv[j] = bf16s(v0[j]);
        int rbase = row0 + s * 32;
#pragma unroll
        for (int ct = 0; ct < 5; ++ct) {
            int4 araw = *(const int4*)(labT + (size_t)(ct * 16 + col) * NROWS + rbase + q * 8);
            short8 af = __builtin_bit_cast(short8, araw);
            acc[ct] = __builtin_amdgcn_mfma_f32_16x16x32_bf16(af, bfv, acc[ct], 0, 0, 0);
        }
#pragma unroll
        for (int j = 0; j < 8; ++j) { v0[j] = v1[j]; v1[j] = vt[j]; }
    }
    float* pb = partial + (size_t)ks * CPAD * NDIM;
#pragma unroll
    for (int ct = 0; ct < 5; ++ct)
#pragma unroll
        for (int reg = 0; reg < 4; ++reg)
            pb[(size_t)(ct * 16 + q * 4 + reg) * NDIM + d] = acc[ct][reg];
}

// ---- K2b1: reduce partial slabs -> mean anchors (f32) + norm2 atomics ----
__global__ __launch_bounds__(256) void k2b1_reduce(const unsigned* __restrict__ counts,
                                                   const float* __restrict__ partial,
                                                   int kslices,
                                                   float* __restrict__ af32,
                                                   float* __restrict__ norm2) {
    int c = blockIdx.x >> 2, dq = blockIdx.x & 3;
    int t = threadIdx.x;
    int d = dq * 256 + t;
    const float* p = partial + (size_t)c * NDIM + d;
    float s = 0.f;
#pragma unroll 8
    for (int sl = 0; sl < kslices; ++sl)
        s += p[(size_t)sl * CPAD * NDIM];
    unsigned cnt = counts[c];
    float invc = 1.0f / (float)(cnt > 0u ? cnt : 1u);
    float a = s * invc;
    af32[(size_t)c * NDIM + d] = a;
    float ss = a * a;
    __shared__ float red[4];
#pragma unroll
    for (int m = 32; m >= 1; m >>= 1) ss += __shfl_xor(ss, m, 64);
    if ((t & 63) == 0) red[t >> 6] = ss;
    __syncthreads();
    if (t == 0) atomicAdd(&norm2[c], red[0] + red[1] + red[2] + red[3]);
}

// ---- K2b2: unit anchors -> bf16, per-c scale = w/||abf||, active bits ----
__global__ __launch_bounds__(256) void k2b2_norm(const float* __restrict__ wptr,
                                                 const unsigned* __restrict__ counts,
                                                 const float* __restrict__ af32,
                                                 const float* __restrict__ norm2,
                                                 unsigned short* __restrict__ abf,
                                                 float* __restrict__ scale,
                                                 unsigned* __restrict__ act) {
    int c = blockIdx.x, t = threadIdx.x;
    int d0 = t * 4;
    float denom = fmaxf(sqrtf(norm2[c]), 1e-8f);   // an = max(||anchor||, eps)
    float rinv = 1.0f / denom;
    float4 a = *(const float4*)(af32 + (size_t)c * NDIM + d0);
    unsigned short h0 = bf16u(a.x * rinv), h1 = bf16u(a.y * rinv);
    unsigned short h2 = bf16u(a.z * rinv), h3 = bf16u(a.w * rinv);
    *(uint2*)(abf + (size_t)c * NDIM + d0) =
        make_uint2(((unsigned)h1 << 16) | h0, ((unsigned)h3 << 16) | h2);
    float f0 = __bfloat162float(__builtin_bit_cast(__hip_bfloat16, h0));
    float f1 = __bfloat162float(__builtin_bit_cast(__hip_bfloat16, h1));
    float f2 = __bfloat162float(__builtin_bit_cast(__hip_bfloat16, h2));
    float f3 = __bfloat162float(__builtin_bit_cast(__hip_bfloat16, h3));
    float nb2 = f0 * f0 + f1 * f1 + f2 * f2 + f3 * f3;
    __shared__ float red[4];
#pragma unroll
    for (int m = 32; m >= 1; m >>= 1) nb2 += __shfl_xor(nb2, m, 64);
    if ((t & 63) == 0) red[t >> 6] = nb2;
    __syncthreads();
    if (t == 0) {
        float n2 = red[0] + red[1] + red[2] + red[3];
        scale[c] = (n2 > 0.f) ? (wptr[0] / sqrtf(n2)) : 0.f;
        unsigned cnt = counts[c];
        if (cnt > 0u) atomicOr(&act[c >> 4], 1u << (c & 15));
    }
}

// ---- K3: cos GEMM barrier-free; A-frags from fp32 x, depth-2 float4 prefetch;
// k-split x4 per block; fused log-softmax pair loss. ----
__global__ __launch_bounds__(256, 4) void k3_loss(const float* __restrict__ x,
                                                  const unsigned short* __restrict__ abf,
                                                  const unsigned long long* __restrict__ masks,
                                                  const unsigned* __restrict__ act,
                                                  const float* __restrict__ scale,
                                                  const float* __restrict__ bptr,
                                                  float* __restrict__ wsum) {
    __shared__ float xch[3][64 * 21];
    int t = threadIdx.x, kh = t >> 6, lane = t & 63;
    int q = lane >> 4, col = lane & 15;
    int rowbase = blockIdx.x * 16;

    const float* arow = x + (size_t)(rowbase + col) * NDIM + kh * 256 + q * 8;
    const unsigned short* bbase = abf + (size_t)col * NDIM + kh * 256 + q * 8;

    float4v acc[5];
#pragma unroll
    for (int ct = 0; ct < 5; ++ct) acc[ct] = (float4v){0.f, 0.f, 0.f, 0.f};
    float sq = 0.f;

    float4 a0 = *(const float4*)(arow + 0);
    float4 a1 = *(const float4*)(arow + 4);
    float4 b0 = *(const float4*)(arow + 32);
    float4 b1 = *(const float4*)(arow + 36);

    for (int s = 0; s < 8; ++s) {
        float4 f0 = a0, f1 = a1;
        a0 = b0; a1 = b1;
        if (s + 2 < 8) {
            const float* np = arow + (s + 2) * 32;
            b0 = *(const float4*)(np);
            b1 = *(const float4*)(np + 4);
        }
        sq += f0.x * f0.x + f0.y * f0.y + f0.z * f0.z + f0.w * f0.w
            + f1.x * f1.x + f1.y * f1.y + f1.z * f1.z + f1.w * f1.w;
        short8 af;
        af[0] = bf16s(f0.x); af[1] = bf16s(f0.y); af[2] = bf16s(f0.z); af[3] = bf16s(f0.w);
        af[4] = bf16s(f1.x); af[5] = bf16s(f1.y); af[6] = bf16s(f1.z); af[7] = bf16s(f1.w);
        int k0 = s * 32;
#pragma unroll
        for (int ct = 0; ct < 5; ++ct) {
            int4 braw = *(const int4*)(bbase + (size_t)ct * 16 * NDIM + k0);
            short8 bf = __builtin_bit_cast(short8, braw);
            acc[ct] = __builtin_amdgcn_mfma_f32_16x16x32_bf16(af, bf, acc[ct], 0, 0, 0);
        }
    }
    sq += __shfl_xor(sq, 16, 64);
    sq += __shfl_xor(sq, 32, 64);   // lane: quarter-norm^2 of row rowbase+(lane&15)

    if (kh) {
        float* dst = &xch[kh - 1][lane * 21];
#pragma unroll
        for (int ct = 0; ct < 5; ++ct)
#pragma unroll
            for (int r = 0; r < 4; ++r) dst[ct * 4 + r] = acc[ct][r];
        dst[20] = sq;
    }
    __syncthreads();
    if (kh) return;
#pragma unroll
    for (int j = 0; j < 3; ++j) {
        const float* src = &xch[j][lane * 21];
#pragma unroll
        for (int ct = 0; ct < 5; ++ct)
#pragma unroll
            for (int r = 0; r < 4; ++r) acc[ct][r] += src[ct * 4 + r];
        sq += src[20];
    }

    float bv = bptr[0];
    float sc[5]; unsigned ab[5];
#pragma unroll
    for (int ct = 0; ct < 5; ++ct) { sc[ct] = scale[ct * 16 + col]; ab[ct] = act[ct]; }

    float contrib = 0.f;
#pragma unroll
    for (int reg = 0; reg < 4; ++reg) {
        int rl = q * 4 + reg;
        int row = rowbase + rl;
        float xn2 = __shfl(sq, (lane & 48) | rl, 64);
        float inv = 1.0f / fmaxf(sqrtf(xn2), 1e-8f);
        unsigned long long mask = masks[row];
        float v[5]; float lmax = -1e30f;
#pragma unroll
        for (int ct = 0; ct < 5; ++ct) {
            float lg = acc[ct][reg] * sc[ct] * inv + bv;   // w*cos + b
            bool a = (ab[ct] >> col) & 1u;
            v[ct] = a ? lg : -1e30f;
            lmax = fmaxf(lmax, v[ct]);
        }
#pragma unroll
        for (int m = 1; m < 16; m <<= 1) lmax = fmaxf(lmax, __shfl_xor(lmax, m, 16));
        float es = 0.f;
#pragma unroll
        for (int ct = 0; ct < 5; ++ct) es += expf(v[ct] - lmax);
#pragma unroll
        for (int m = 1; m < 16; m <<= 1) es += __shfl_xor(es, m, 16);
        float lse = lmax + logf(es);
        float ps = 0.f;
#pragma unroll
        for (int ct = 0; ct < 5; ++ct) {
            int c = ct * 16 + col;
            bool pos = (c < 64) ? (((mask >> c) & 1ull) != 0ull)
                                : ((c == 64) ? (mask == 0ull) : false);
            ps += pos ? v[ct] : 0.f;
        }
#pragma unroll
        for (int m = 1; m < 16; m <<= 1) ps += __shfl_xor(ps, m, 16);
        float npos = mask ? (float)__popcll(mask) : 1.0f;
        float crow = ps - npos * lse;
        if (col == 0) contrib += crow;
    }
#pragma unroll
    for (int m = 1; m < 64; m <<= 1) contrib += __shfl_xor(contrib, m, 64);
    if (lane == 0) atomicAdd(wsum, contrib);
}

// ---- K4: loss = -sum(logp over positive pairs) / n_pairs ----
__global__ void k4_final(const unsigned* __restrict__ counts,
                         const float* __restrict__ wsum,
                         float* __restrict__ out) {
    if (threadIdx.x == 0 && blockIdx.x == 0) {
        float np = 0.f;
        for (int c = 0; c < NC; ++c) np += (float)counts[c];
        out[0] = -wsum[0] / np;
    }
}

extern "C" void kernel_launch(void* const* d_in, const int* in_sizes, int n_in,
                              void* d_out, int out_size, void* d_ws, size_t ws_size,
                              hipStream_t stream) {
    (void)in_sizes; (void)n_in; (void)out_size;
    const float* x = (const float*)d_in[0];
    const int* label = (const int*)d_in[1];
    const float* w = (const float*)d_in[2];
    const float* b = (const float*)d_in[3];

    char* ws = (char*)d_ws;
    unsigned* counts = (unsigned*)(ws + CNT_B);
    unsigned* act = (unsigned*)(ws + ACT_B);
    float* scale = (float*)(ws + SCALE_B);
    float* wsum = (float*)(ws + WSUM_B);
    float* norm2 = (float*)(ws + NORM2_B);
    unsigned long long* masks = (unsigned long long*)(ws + MASK_B);
    unsigned short* abf = (unsigned short*)(ws + ABF_B);
    unsigned short* labT = (unsigned short*)(ws + LABT_B);
    float* af32 = (float*)(ws + AF32_B);
    float* partial = (float*)(ws + PART_B);

    int kslices = 64;
    while (kslices > 8 && PART_B + (size_t)kslices * SLAB > ws_size) kslices >>= 1;

    hipMemsetAsync(d_ws, 0, ZERO_BYTES, stream);
    hipLaunchKernelGGL(k1_labels, dim3(256), dim3(256), 0, stream, label, masks, counts, labT);
    hipLaunchKernelGGL(k2_sums, dim3(16 * kslices), dim3(256), 0, stream, x, labT, partial, kslices);
    hipLaunchKernelGGL(k2b1_reduce, dim3(CPAD * 4), dim3(256), 0, stream,
                       counts, partial, kslices, af32, norm2);
    hipLaunchKernelGGL(k2b2_norm, dim3(CPAD), dim3(256), 0, stream,
                       w, counts, af32, norm2, abf, scale, act);
    hipLaunchKernelGGL(k3_loss, dim3(NROWS / 16), dim3(256), 0, stream,
                       x, abf, masks, act, scale, b, wsum);
    hipLaunchKernelGGL(k4_final, dim3(1), dim3(64), 0, stream, counts, wsum, (float*)d_out);
}

// Round 6
// 169.510 us; speedup vs baseline: 1.1550x; 1.1377x over previous
//
#include <hip/hip_runtime.h>
#include <hip/hip_bf16.h>
#include <stdint.h>

#define NROWS 16384
#define NDIM  1024
#define NLAB  64
#define NC    65
#define CPAD  80

typedef float float4v __attribute__((ext_vector_type(4)));
typedef short short8  __attribute__((ext_vector_type(8)));

// ---- workspace layout (bytes) ----
static constexpr size_t CNT_B   = 0;         // 80 u32 counts
static constexpr size_t ACT_B   = 320;       // 8 u32 active bitfields
static constexpr size_t SCALE_B = 352;       // 80 f32 (w/||abf_c||)
static constexpr size_t WSUM_B  = 672;       // f32 loss accumulator
static constexpr size_t NORM2_B = 704;       // 80 f32 ||anchor||^2
static constexpr size_t ZERO_BYTES = 1024;
static constexpr size_t MASK_B  = 1024;      // 16384 u64 row masks
static constexpr size_t XN2_B   = 132096;    // 16384 f32 row norms^2
static constexpr size_t LFRAG_B = 197632;    // 80c x 16384rows bf16, A-frag layout
static constexpr size_t BFRAG_B = 2819072;   // 80c x 1024d bf16 unit anchors, B-frag layout
static constexpr size_t AF32_B  = 2982912;   // 80x1024 f32 mean anchors
static constexpr size_t XAF_B   = 3310592;   // x bf16 in A-frag layout (32 MB)
static constexpr size_t XCOL_B  = 36865024;  // x bf16 col-major 16-row tiles (32 MB)
static constexpr size_t PART_B  = 70419456;  // kslices*80*1024 f32 partials
static constexpr size_t SLAB    = (size_t)CPAD * NDIM * 4;

__device__ __forceinline__ unsigned short bf16u(float f) {
    __hip_bfloat16 h = __float2bfloat16(f);
    return __builtin_bit_cast(unsigned short, h);
}
__device__ __forceinline__ unsigned pk2(float a, float b) {
    return (unsigned)bf16u(a) | ((unsigned)bf16u(b) << 16);
}

// ---- K0: x -> xAfrag (A-frag layout), xcol (16-row col-major tiles), xn2 ----
__global__ __launch_bounds__(256) void k0_prep(const float* __restrict__ x,
                                               unsigned short* __restrict__ xAfrag,
                                               unsigned short* __restrict__ xcol,
                                               float* __restrict__ xn2g) {
    __shared__ unsigned short xt[16][1034];   // [row][dim], pad to stride 517 words
    int t = threadIdx.x;
    int rt = blockIdx.x;                      // 16-row tile
    int r = t >> 4, cpos = t & 15;
    const float* src = x + ((size_t)rt * 16 + r) * NDIM + cpos * 4;
    float sq = 0.f;
#pragma unroll
    for (int i = 0; i < 16; ++i) {
        float4 f = *(const float4*)(src + i * 64);
        sq += f.x * f.x + f.y * f.y + f.z * f.z + f.w * f.w;
        *(uint2*)&xt[r][cpos * 4 + i * 64] = make_uint2(pk2(f.x, f.y), pk2(f.z, f.w));
    }
#pragma unroll
    for (int m = 1; m < 16; m <<= 1) sq += __shfl_xor(sq, m, 16);
    if (cpos == 0) xn2g[rt * 16 + r] = sq;
    __syncthreads();
    // xAfrag: chunk (rt,kb) slot=lane: x[rt*16+col][kb*32+q*8 ..+8]; writes coalesced
    {
        int slot = t & 63, wv = t >> 6;
        int q = slot >> 4, col = slot & 15;
#pragma unroll
        for (int s = 0; s < 8; ++s) {
            int kb = s * 4 + wv;
            uint4 v = *(const uint4*)&xt[col][kb * 32 + q * 8];
            ((uint4*)xAfrag)[((size_t)rt * 32 + kb) * 64 + slot] = v;
        }
    }
    // xcol: [rt][dim][16 rows]; gather per-dim columns, coalesced 16B stores
#pragma unroll
    for (int s = 0; s < 8; ++s) {
        int dim = s * 128 + (t >> 1);
        int rh = (t & 1) * 8;
        unsigned short tmp[8];
#pragma unroll
        for (int j = 0; j < 8; ++j) tmp[j] = xt[rh + j][dim];
        uint4 v;
        v.x = (unsigned)tmp[0] | ((unsigned)tmp[1] << 16);
        v.y = (unsigned)tmp[2] | ((unsigned)tmp[3] << 16);
        v.z = (unsigned)tmp[4] | ((unsigned)tmp[5] << 16);
        v.w = (unsigned)tmp[6] | ((unsigned)tmp[7] << 16);
        ((uint4*)xcol)[(size_t)rt * 2048 + s * 256 + t] = v;
    }
}

// ---- K1: masks + counts + lfrag (labT in A-frag layout) ----
__global__ __launch_bounds__(256) void k1_labels(const int* __restrict__ label,
                                                 unsigned long long* __restrict__ masks,
                                                 unsigned* __restrict__ counts,
                                                 unsigned short* __restrict__ lfrag) {
    __shared__ unsigned cnt[NC];
    __shared__ unsigned long long smask[64];
    int t = threadIdx.x;
    if (t < NC) cnt[t] = 0;
    __syncthreads();
    int wave = t >> 6, lane = t & 63;
    int rowblock = blockIdx.x * 64;
    unsigned creg = 0, zreg = 0;
#pragma unroll 4
    for (int p = 0; p < 16; ++p) {
        int row = rowblock + p * 4 + wave;
        int v = label[row * NLAB + lane];
        unsigned long long m = __ballot(v != 0);
        creg += (unsigned)((m >> lane) & 1ull);
        if (lane == 0) {
            masks[row] = m;
            smask[p * 4 + wave] = m;
            zreg += (m == 0ull) ? 1u : 0u;
        }
    }
    atomicAdd(&cnt[lane], creg);
    if (lane == 0 && zreg) atomicAdd(&cnt[64], zreg);
    __syncthreads();
    if (t < NC) atomicAdd(&counts[t], cnt[t]);
    // lfrag chunks: ((g_rt2*5 + ct)*64 + lane)*8 shorts; 2 rt2-blocks of 32 rows here
    for (int pid = t; pid < 640; pid += 256) {
        int rt2l = pid / 320, rem = pid % 320;
        int ct = rem >> 6, ln = rem & 63;
        int q = ln >> 4, col = ln & 15;
        int c = ct * 16 + col;
        int rbase = rt2l * 32 + q * 8;
        unsigned pk[4];
#pragma unroll
        for (int jp = 0; jp < 4; ++jp) {
            unsigned long long m0 = smask[rbase + jp * 2], m1 = smask[rbase + jp * 2 + 1];
            unsigned b0, b1;
            if (c < 64)       { b0 = (unsigned)((m0 >> c) & 1ull); b1 = (unsigned)((m1 >> c) & 1ull); }
            else if (c == 64) { b0 = (m0 == 0ull); b1 = (m1 == 0ull); }
            else              { b0 = 0u; b1 = 0u; }
            pk[jp] = (b0 ? 0x3F80u : 0u) | (b1 ? 0x3F800000u : 0u);
        }
        uint4 w = make_uint4(pk[0], pk[1], pk[2], pk[3]);
        ((uint4*)lfrag)[((size_t)(blockIdx.x * 2 + rt2l) * 5 + ct) * 64 + ln] = w;
    }
}

// ---- K2: sums = labT @ x; all-contiguous frag loads, barrier-free ----
__global__ __launch_bounds__(256) void k2_sums(const unsigned short* __restrict__ xcol,
                                               const unsigned short* __restrict__ lfrag,
                                               float* __restrict__ partial,
                                               int kslices) {
    int t = threadIdx.x, wave = t >> 6, lane = t & 63;
    int q = lane >> 4, col = lane & 15;
    int dgroup = blockIdx.x & 15, ks = blockIdx.x >> 4;
    int nkb = (NROWS / kslices) >> 5;
    int kb0 = ks * nkb;
    int d = dgroup * 64 + wave * 16 + col;
    const uint4* B = (const uint4*)xcol;
    const uint4* A = (const uint4*)lfrag;
    size_t bidx0 = (size_t)d * 2 + (q & 1);
    int qh = q >> 1;

    float4v acc[5];
#pragma unroll
    for (int ct = 0; ct < 5; ++ct) acc[ct] = (float4v){0.f, 0.f, 0.f, 0.f};

#pragma unroll 4
    for (int i = 0; i < nkb; ++i) {
        int kb = kb0 + i;
        uint4 braw = B[(size_t)(kb * 2 + qh) * 2048 + bidx0];
        short8 bf = __builtin_bit_cast(short8, braw);
#pragma unroll
        for (int ct = 0; ct < 5; ++ct) {
            uint4 araw = A[((size_t)kb * 5 + ct) * 64 + lane];
            short8 af = __builtin_bit_cast(short8, araw);
            acc[ct] = __builtin_amdgcn_mfma_f32_16x16x32_bf16(af, bf, acc[ct], 0, 0, 0);
        }
    }
    float* pb = partial + (size_t)ks * CPAD * NDIM;
#pragma unroll
    for (int ct = 0; ct < 5; ++ct)
#pragma unroll
        for (int reg = 0; reg < 4; ++reg)
            pb[(size_t)(ct * 16 + q * 4 + reg) * NDIM + d] = acc[ct][reg];
}

// ---- K2b1: reduce partial slabs -> mean anchors (f32) + norm2 atomics ----
__global__ __launch_bounds__(256) void k2b1_reduce(const unsigned* __restrict__ counts,
                                                   const float* __restrict__ partial,
                                                   int kslices,
                                                   float* __restrict__ af32,
                                                   float* __restrict__ norm2) {
    int c = blockIdx.x >> 2, dq = blockIdx.x & 3;
    int t = threadIdx.x;
    int d = dq * 256 + t;
    const float* p = partial + (size_t)c * NDIM + d;
    float s = 0.f;
#pragma unroll 8
    for (int sl = 0; sl < kslices; ++sl)
        s += p[(size_t)sl * CPAD * NDIM];
    unsigned cnt = counts[c];
    float invc = 1.0f / (float)(cnt > 0u ? cnt : 1u);
    float a = s * invc;
    af32[(size_t)c * NDIM + d] = a;
    float ss = a * a;
    __shared__ float red[4];
#pragma unroll
    for (int m = 32; m >= 1; m >>= 1) ss += __shfl_xor(ss, m, 64);
    if ((t & 63) == 0) red[t >> 6] = ss;
    __syncthreads();
    if (t == 0) atomicAdd(&norm2[c], red[0] + red[1] + red[2] + red[3]);
}

// ---- K2b2: unit anchors -> bfrag (B-frag layout), per-c scale, active bits ----
__global__ __launch_bounds__(256) void k2b2_norm(const float* __restrict__ wptr,
                                                 const unsigned* __restrict__ counts,
                                                 const float* __restrict__ af32,
                                                 const float* __restrict__ norm2,
                                                 unsigned short* __restrict__ bfrag,
                                                 float* __restrict__ scale,
                                                 unsigned* __restrict__ act) {
    int c = blockIdx.x, t = threadIdx.x;
    int d0 = t * 4;
    float denom = fmaxf(sqrtf(norm2[c]), 1e-8f);
    float rinv = 1.0f / denom;
    float4 a = *(const float4*)(af32 + (size_t)c * NDIM + d0);
    unsigned short h0 = bf16u(a.x * rinv), h1 = bf16u(a.y * rinv);
    unsigned short h2 = bf16u(a.z * rinv), h3 = bf16u(a.w * rinv);
    // B-frag slot: chunk (ct, kb), lane (q, colc), elems j
    int ct = c >> 4, colc = c & 15;
    int kb = d0 >> 5, q = (d0 >> 3) & 3, j0 = d0 & 7;
    size_t sidx = ((((size_t)ct * 32 + kb) * 64) + q * 16 + colc) * 8 + j0;
    *(uint2*)(bfrag + sidx) =
        make_uint2(((unsigned)h1 << 16) | h0, ((unsigned)h3 << 16) | h2);
    float f0 = __bfloat162float(__builtin_bit_cast(__hip_bfloat16, h0));
    float f1 = __bfloat162float(__builtin_bit_cast(__hip_bfloat16, h1));
    float f2 = __bfloat162float(__builtin_bit_cast(__hip_bfloat16, h2));
    float f3 = __bfloat162float(__builtin_bit_cast(__hip_bfloat16, h3));
    float nb2 = f0 * f0 + f1 * f1 + f2 * f2 + f3 * f3;
    __shared__ float red[4];
#pragma unroll
    for (int m = 32; m >= 1; m >>= 1) nb2 += __shfl_xor(nb2, m, 64);
    if ((t & 63) == 0) red[t >> 6] = nb2;
    __syncthreads();
    if (t == 0) {
        float n2 = red[0] + red[1] + red[2] + red[3];
        scale[c] = (n2 > 0.f) ? (wptr[0] / sqrtf(n2)) : 0.f;
        if (counts[c] > 0u) atomicOr(&act[c >> 4], 1u << (c & 15));
    }
}

// ---- K3: cos GEMM, all-contiguous frag loads, barrier-free k-split x4 ----
__global__ __launch_bounds__(256, 4) void k3_loss(const unsigned short* __restrict__ xAfrag,
                                                  const unsigned short* __restrict__ bfrag,
                                                  const float* __restrict__ xn2g,
                                                  const unsigned long long* __restrict__ masks,
                                                  const unsigned* __restrict__ act,
                                                  const float* __restrict__ scale,
                                                  const float* __restrict__ bptr,
                                                  float* __restrict__ wsum) {
    __shared__ float xch[3][64 * 20];
    int t = threadIdx.x, kh = t >> 6, lane = t & 63;
    int q = lane >> 4, col = lane & 15;
    int rt = blockIdx.x;
    int rowbase = rt * 16;
    const uint4* A = (const uint4*)xAfrag;
    const uint4* B = (const uint4*)bfrag;

    float4v acc[5];
#pragma unroll
    for (int ct = 0; ct < 5; ++ct) acc[ct] = (float4v){0.f, 0.f, 0.f, 0.f};

#pragma unroll
    for (int s = 0; s < 8; ++s) {
        int kb = kh * 8 + s;
        uint4 araw = A[((size_t)rt * 32 + kb) * 64 + lane];
        short8 af = __builtin_bit_cast(short8, araw);
#pragma unroll
        for (int ct = 0; ct < 5; ++ct) {
            uint4 braw = B[((size_t)ct * 32 + kb) * 64 + lane];
            short8 bf = __builtin_bit_cast(short8, braw);
            acc[ct] = __builtin_amdgcn_mfma_f32_16x16x32_bf16(af, bf, acc[ct], 0, 0, 0);
        }
    }
    if (kh) {
        float* dst = &xch[kh - 1][lane * 20];
#pragma unroll
        for (int ct = 0; ct < 5; ++ct)
#pragma unroll
            for (int r = 0; r < 4; ++r) dst[ct * 4 + r] = acc[ct][r];
    }
    __syncthreads();
    if (kh) return;
#pragma unroll
    for (int j = 0; j < 3; ++j) {
        const float* src = &xch[j][lane * 20];
#pragma unroll
        for (int ct = 0; ct < 5; ++ct)
#pragma unroll
            for (int r = 0; r < 4; ++r) acc[ct][r] += src[ct * 4 + r];
    }

    float bv = bptr[0];
    float sc[5]; unsigned ab[5];
#pragma unroll
    for (int ct = 0; ct < 5; ++ct) { sc[ct] = scale[ct * 16 + col]; ab[ct] = act[ct]; }

    float contrib = 0.f;
#pragma unroll
    for (int reg = 0; reg < 4; ++reg) {
        int rl = q * 4 + reg;
        int row = rowbase + rl;
        float inv = 1.0f / fmaxf(sqrtf(xn2g[row]), 1e-8f);
        unsigned long long mask = masks[row];
        float v[5]; float lmax = -1e30f;
#pragma unroll
        for (int ct = 0; ct < 5; ++ct) {
            float lg = acc[ct][reg] * sc[ct] * inv + bv;   // w*cos + b
            bool a = (ab[ct] >> col) & 1u;
            v[ct] = a ? lg : -1e30f;
            lmax = fmaxf(lmax, v[ct]);
        }
#pragma unroll
        for (int m = 1; m < 16; m <<= 1) lmax = fmaxf(lmax, __shfl_xor(lmax, m, 16));
        float es = 0.f;
#pragma unroll
        for (int ct = 0; ct < 5; ++ct) es += expf(v[ct] - lmax);
#pragma unroll
        for (int m = 1; m < 16; m <<= 1) es += __shfl_xor(es, m, 16);
        float lse = lmax + logf(es);
        float ps = 0.f;
#pragma unroll
        for (int ct = 0; ct < 5; ++ct) {
            int c = ct * 16 + col;
            bool pos = (c < 64) ? (((mask >> c) & 1ull) != 0ull)
                                : ((c == 64) ? (mask == 0ull) : false);
            ps += pos ? v[ct] : 0.f;
        }
#pragma unroll
        for (int m = 1; m < 16; m <<= 1) ps += __shfl_xor(ps, m, 16);
        float npos = mask ? (float)__popcll(mask) : 1.0f;
        float crow = ps - npos * lse;
        if (col == 0) contrib += crow;
    }
#pragma unroll
    for (int m = 1; m < 64; m <<= 1) contrib += __shfl_xor(contrib, m, 64);
    if (lane == 0) atomicAdd(wsum, contrib);
}

// ---- K4: loss = -sum(logp over positive pairs) / n_pairs ----
__global__ void k4_final(const unsigned* __restrict__ counts,
                         const float* __restrict__ wsum,
                         float* __restrict__ out) {
    if (threadIdx.x == 0 && blockIdx.x == 0) {
        float np = 0.f;
        for (int c = 0; c < NC; ++c) np += (float)counts[c];
        out[0] = -wsum[0] / np;
    }
}

extern "C" void kernel_launch(void* const* d_in, const int* in_sizes, int n_in,
                              void* d_out, int out_size, void* d_ws, size_t ws_size,
                              hipStream_t stream) {
    (void)in_sizes; (void)n_in; (void)out_size;
    const float* x = (const float*)d_in[0];
    const int* label = (const int*)d_in[1];
    const float* w = (const float*)d_in[2];
    const float* b = (const float*)d_in[3];

    char* ws = (char*)d_ws;
    unsigned* counts = (unsigned*)(ws + CNT_B);
    unsigned* act = (unsigned*)(ws + ACT_B);
    float* scale = (float*)(ws + SCALE_B);
    float* wsum = (float*)(ws + WSUM_B);
    float* norm2 = (float*)(ws + NORM2_B);
    unsigned long long* masks = (unsigned long long*)(ws + MASK_B);
    float* xn2g = (float*)(ws + XN2_B);
    unsigned short* lfrag = (unsigned short*)(ws + LFRAG_B);
    unsigned short* bfrag = (unsigned short*)(ws + BFRAG_B);
    float* af32 = (float*)(ws + AF32_B);
    unsigned short* xAfrag = (unsigned short*)(ws + XAF_B);
    unsigned short* xcol = (unsigned short*)(ws + XCOL_B);
    float* partial = (float*)(ws + PART_B);

    int kslices = 32;
    while (kslices > 8 && PART_B + (size_t)kslices * SLAB > ws_size) kslices >>= 1;

    hipMemsetAsync(d_ws, 0, ZERO_BYTES, stream);
    hipLaunchKernelGGL(k0_prep, dim3(NROWS / 16), dim3(256), 0, stream, x, xAfrag, xcol, xn2g);
    hipLaunchKernelGGL(k1_labels, dim3(256), dim3(256), 0, stream, label, masks, counts, lfrag);
    hipLaunchKernelGGL(k2_sums, dim3(16 * kslices), dim3(256), 0, stream,
                       xcol, lfrag, partial, kslices);
    hipLaunchKernelGGL(k2b1_reduce, dim3(CPAD * 4), dim3(256), 0, stream,
                       counts, partial, kslices, af32, norm2);
    hipLaunchKernelGGL(k2b2_norm, dim3(CPAD), dim3(256), 0, stream,
                       w, counts, af32, norm2, bfrag, scale, act);
    hipLaunchKernelGGL(k3_loss, dim3(NROWS / 16), dim3(256), 0, stream,
                       xAfrag, bfrag, xn2g, masks, act, scale, b, wsum);
    hipLaunchKernelGGL(k4_final, dim3(1), dim3(64), 0, stream, counts, wsum, (float*)d_out);
}

// Round 7
// 162.262 us; speedup vs baseline: 1.2065x; 1.0447x over previous
//
#include <hip/hip_runtime.h>
#include <hip/hip_bf16.h>
#include <stdint.h>

#define NROWS 16384
#define NDIM  1024
#define NLAB  64
#define NC    65
#define CPAD  80

typedef float float4v __attribute__((ext_vector_type(4)));
typedef short short8  __attribute__((ext_vector_type(8)));

// ---- workspace layout (bytes) ----
static constexpr size_t CNT_B   = 0;         // 80 u32 counts
static constexpr size_t ACT_B   = 320;       // 8 u32 active bitfields
static constexpr size_t SCALE_B = 352;       // 80 f32 (w/||abf_c||)
static constexpr size_t WSUM_B  = 672;       // f32 loss accumulator
static constexpr size_t ZERO_BYTES = 676;
static constexpr size_t MASK_B  = 1024;      // 16384 u64 row masks
static constexpr size_t XN2_B   = 132096;    // 16384 f32 row norms^2
static constexpr size_t LFRAG_B = 197632;    // labT bf16, A-frag layout
static constexpr size_t BFRAG_B = 2819072;   // unit anchors bf16, B-frag layout
static constexpr size_t XAF_B   = 2982912;   // x bf16, A-frag layout (32 MB)
static constexpr size_t XCOL_B  = 36537344;  // x bf16, col-major 16-row tiles (32 MB)
static constexpr size_t PART_B  = 70091776;  // kslices*80*1024 f32 partials
static constexpr size_t SLAB    = (size_t)CPAD * NDIM * 4;

__device__ __forceinline__ unsigned short bf16u(float f) {
    __hip_bfloat16 h = __float2bfloat16(f);
    return __builtin_bit_cast(unsigned short, h);
}
__device__ __forceinline__ unsigned pk2(float a, float b) {
    return (unsigned)bf16u(a) | ((unsigned)bf16u(b) << 16);
}

// ---- K01: blocks 0..1023 = x prep (xAfrag/xcol/xn2); 1024..1279 = labels ----
__global__ __launch_bounds__(256) void k01_prep(const float* __restrict__ x,
                                                const int* __restrict__ label,
                                                unsigned short* __restrict__ xAfrag,
                                                unsigned short* __restrict__ xcol,
                                                float* __restrict__ xn2g,
                                                unsigned long long* __restrict__ masks,
                                                unsigned* __restrict__ counts,
                                                unsigned short* __restrict__ lfrag) {
    __shared__ unsigned short xt[16][1034];
    __shared__ unsigned cnt[NC];
    __shared__ unsigned long long smask[64];
    int t = threadIdx.x;
    if (blockIdx.x < 1024) {
        int rt = blockIdx.x;
        int r = t >> 4, cpos = t & 15;
        const float* src = x + ((size_t)rt * 16 + r) * NDIM + cpos * 4;
        float sq = 0.f;
#pragma unroll
        for (int i = 0; i < 16; ++i) {
            float4 f = *(const float4*)(src + i * 64);
            sq += f.x * f.x + f.y * f.y + f.z * f.z + f.w * f.w;
            *(uint2*)&xt[r][cpos * 4 + i * 64] = make_uint2(pk2(f.x, f.y), pk2(f.z, f.w));
        }
#pragma unroll
        for (int m = 1; m < 16; m <<= 1) sq += __shfl_xor(sq, m, 16);
        if (cpos == 0) xn2g[rt * 16 + r] = sq;
        __syncthreads();
        {
            int slot = t & 63, wv = t >> 6;
            int q = slot >> 4, col = slot & 15;
#pragma unroll
            for (int s = 0; s < 8; ++s) {
                int kb = s * 4 + wv;
                uint4 v = *(const uint4*)&xt[col][kb * 32 + q * 8];
                ((uint4*)xAfrag)[((size_t)rt * 32 + kb) * 64 + slot] = v;
            }
        }
#pragma unroll
        for (int s = 0; s < 8; ++s) {
            int dim = s * 128 + (t >> 1);
            int rh = (t & 1) * 8;
            unsigned short tmp[8];
#pragma unroll
            for (int j = 0; j < 8; ++j) tmp[j] = xt[rh + j][dim];
            uint4 v;
            v.x = (unsigned)tmp[0] | ((unsigned)tmp[1] << 16);
            v.y = (unsigned)tmp[2] | ((unsigned)tmp[3] << 16);
            v.z = (unsigned)tmp[4] | ((unsigned)tmp[5] << 16);
            v.w = (unsigned)tmp[6] | ((unsigned)tmp[7] << 16);
            ((uint4*)xcol)[(size_t)rt * 2048 + s * 256 + t] = v;
        }
        return;
    }
    // ---- label path ----
    int bid = blockIdx.x - 1024;
    if (t < NC) cnt[t] = 0;
    __syncthreads();
    int wave = t >> 6, lane = t & 63;
    int rowblock = bid * 64;
    unsigned creg = 0, zreg = 0;
#pragma unroll 4
    for (int p = 0; p < 16; ++p) {
        int row = rowblock + p * 4 + wave;
        int v = label[row * NLAB + lane];
        unsigned long long m = __ballot(v != 0);
        creg += (unsigned)((m >> lane) & 1ull);
        if (lane == 0) {
            masks[row] = m;
            smask[p * 4 + wave] = m;
            zreg += (m == 0ull) ? 1u : 0u;
        }
    }
    atomicAdd(&cnt[lane], creg);
    if (lane == 0 && zreg) atomicAdd(&cnt[64], zreg);
    __syncthreads();
    if (t < NC) atomicAdd(&counts[t], cnt[t]);
    for (int pid = t; pid < 640; pid += 256) {
        int rt2l = pid / 320, rem = pid % 320;
        int ct = rem >> 6, ln = rem & 63;
        int q = ln >> 4, col = ln & 15;
        int c = ct * 16 + col;
        int rbase = rt2l * 32 + q * 8;
        unsigned pk[4];
#pragma unroll
        for (int jp = 0; jp < 4; ++jp) {
            unsigned long long m0 = smask[rbase + jp * 2], m1 = smask[rbase + jp * 2 + 1];
            unsigned b0, b1;
            if (c < 64)       { b0 = (unsigned)((m0 >> c) & 1ull); b1 = (unsigned)((m1 >> c) & 1ull); }
            else if (c == 64) { b0 = (m0 == 0ull); b1 = (m1 == 0ull); }
            else              { b0 = 0u; b1 = 0u; }
            pk[jp] = (b0 ? 0x3F80u : 0u) | (b1 ? 0x3F800000u : 0u);
        }
        uint4 w = make_uint4(pk[0], pk[1], pk[2], pk[3]);
        ((uint4*)lfrag)[((size_t)(bid * 2 + rt2l) * 5 + ct) * 64 + ln] = w;
    }
}

// ---- K2: sums = labT @ x; all-contiguous frag loads, barrier-free ----
__global__ __launch_bounds__(256) void k2_sums(const unsigned short* __restrict__ xcol,
                                               const unsigned short* __restrict__ lfrag,
                                               float* __restrict__ partial,
                                               int kslices) {
    int t = threadIdx.x, wave = t >> 6, lane = t & 63;
    int q = lane >> 4, col = lane & 15;
    int dgroup = blockIdx.x & 15, ks = blockIdx.x >> 4;
    int nkb = (NROWS / kslices) >> 5;
    int kb0 = ks * nkb;
    int d = dgroup * 64 + wave * 16 + col;
    const uint4* B = (const uint4*)xcol;
    const uint4* A = (const uint4*)lfrag;
    size_t bidx0 = (size_t)d * 2 + (q & 1);
    int qh = q >> 1;

    float4v acc[5];
#pragma unroll
    for (int ct = 0; ct < 5; ++ct) acc[ct] = (float4v){0.f, 0.f, 0.f, 0.f};

#pragma unroll 4
    for (int i = 0; i < nkb; ++i) {
        int kb = kb0 + i;
        uint4 braw = B[(size_t)(kb * 2 + qh) * 2048 + bidx0];
        short8 bf = __builtin_bit_cast(short8, braw);
#pragma unroll
        for (int ct = 0; ct < 5; ++ct) {
            uint4 araw = A[((size_t)kb * 5 + ct) * 64 + lane];
            short8 af = __builtin_bit_cast(short8, araw);
            acc[ct] = __builtin_amdgcn_mfma_f32_16x16x32_bf16(af, bf, acc[ct], 0, 0, 0);
        }
    }
    float* pb = partial + (size_t)ks * CPAD * NDIM;
#pragma unroll
    for (int ct = 0; ct < 5; ++ct)
#pragma unroll
        for (int reg = 0; reg < 4; ++reg)
            pb[(size_t)(ct * 16 + q * 4 + reg) * NDIM + d] = acc[ct][reg];
}

// ---- K2b (fused): reduce slabs -> unit anchor bf16 in B-frag layout + scale ----
__global__ __launch_bounds__(256) void k2b_fuse(const float* __restrict__ wptr,
                                                const unsigned* __restrict__ counts,
                                                const float* __restrict__ partial,
                                                int kslices,
                                                unsigned short* __restrict__ bfrag,
                                                float* __restrict__ scale,
                                                unsigned* __restrict__ act) {
    int c = blockIdx.x, t = threadIdx.x;
    int d0 = t * 4;
    const float* p = partial + (size_t)c * NDIM + d0;
    float4 s = make_float4(0.f, 0.f, 0.f, 0.f);
#pragma unroll 8
    for (int sl = 0; sl < kslices; ++sl) {
        float4 v = *(const float4*)(p + (size_t)sl * CPAD * NDIM);
        s.x += v.x; s.y += v.y; s.z += v.z; s.w += v.w;
    }
    unsigned cnt = counts[c];
    float invc = 1.0f / (float)(cnt > 0u ? cnt : 1u);
    float ax = s.x * invc, ay = s.y * invc, az = s.z * invc, aw = s.w * invc;
    float ss = ax * ax + ay * ay + az * az + aw * aw;
    __shared__ float red[8];
#pragma unroll
    for (int m = 32; m >= 1; m >>= 1) ss += __shfl_xor(ss, m, 64);
    if ((t & 63) == 0) red[t >> 6] = ss;
    __syncthreads();
    ss = red[0] + red[1] + red[2] + red[3];

    float denom = fmaxf(sqrtf(ss), 1e-8f);   // an = max(||anchor||, eps)
    float rinv = invc / denom;
    unsigned short h0 = bf16u(s.x * rinv), h1 = bf16u(s.y * rinv);
    unsigned short h2 = bf16u(s.z * rinv), h3 = bf16u(s.w * rinv);
    // B-frag slot: chunk (ct, kb), lane (q, colc), elems j
    int ct = c >> 4, colc = c & 15;
    int kb = d0 >> 5, q = (d0 >> 3) & 3, j0 = d0 & 7;
    size_t sidx = ((((size_t)ct * 32 + kb) * 64) + q * 16 + colc) * 8 + j0;
    *(uint2*)(bfrag + sidx) =
        make_uint2(((unsigned)h1 << 16) | h0, ((unsigned)h3 << 16) | h2);

    float f0 = __bfloat162float(__builtin_bit_cast(__hip_bfloat16, h0));
    float f1 = __bfloat162float(__builtin_bit_cast(__hip_bfloat16, h1));
    float f2 = __bfloat162float(__builtin_bit_cast(__hip_bfloat16, h2));
    float f3 = __bfloat162float(__builtin_bit_cast(__hip_bfloat16, h3));
    float nb2 = f0 * f0 + f1 * f1 + f2 * f2 + f3 * f3;
#pragma unroll
    for (int m = 32; m >= 1; m >>= 1) nb2 += __shfl_xor(nb2, m, 64);
    if ((t & 63) == 0) red[4 + (t >> 6)] = nb2;
    __syncthreads();
    if (t == 0) {
        float n2 = red[4] + red[5] + red[6] + red[7];
        scale[c] = (n2 > 0.f) ? (wptr[0] / sqrtf(n2)) : 0.f;
        if (cnt > 0u) atomicOr(&act[c >> 4], 1u << (c & 15));
    }
}

// ---- K3: cos GEMM, all-contiguous frag loads, barrier-free k-split x4 ----
__global__ __launch_bounds__(256, 4) void k3_loss(const unsigned short* __restrict__ xAfrag,
                                                  const unsigned short* __restrict__ bfrag,
                                                  const float* __restrict__ xn2g,
                                                  const unsigned long long* __restrict__ masks,
                                                  const unsigned* __restrict__ act,
                                                  const float* __restrict__ scale,
                                                  const float* __restrict__ bptr,
                                                  float* __restrict__ wsum) {
    __shared__ float xch[3][64 * 20];
    int t = threadIdx.x, kh = t >> 6, lane = t & 63;
    int q = lane >> 4, col = lane & 15;
    int rt = blockIdx.x;
    int rowbase = rt * 16;
    const uint4* A = (const uint4*)xAfrag;
    const uint4* B = (const uint4*)bfrag;

    float4v acc[5];
#pragma unroll
    for (int ct = 0; ct < 5; ++ct) acc[ct] = (float4v){0.f, 0.f, 0.f, 0.f};

#pragma unroll
    for (int s = 0; s < 8; ++s) {
        int kb = kh * 8 + s;
        uint4 araw = A[((size_t)rt * 32 + kb) * 64 + lane];
        short8 af = __builtin_bit_cast(short8, araw);
#pragma unroll
        for (int ct = 0; ct < 5; ++ct) {
            uint4 braw = B[((size_t)ct * 32 + kb) * 64 + lane];
            short8 bf = __builtin_bit_cast(short8, braw);
            acc[ct] = __builtin_amdgcn_mfma_f32_16x16x32_bf16(af, bf, acc[ct], 0, 0, 0);
        }
    }
    if (kh) {
        float* dst = &xch[kh - 1][lane * 20];
#pragma unroll
        for (int ct = 0; ct < 5; ++ct)
#pragma unroll
            for (int r = 0; r < 4; ++r) dst[ct * 4 + r] = acc[ct][r];
    }
    __syncthreads();
    if (kh) return;
#pragma unroll
    for (int j = 0; j < 3; ++j) {
        const float* src = &xch[j][lane * 20];
#pragma unroll
        for (int ct = 0; ct < 5; ++ct)
#pragma unroll
            for (int r = 0; r < 4; ++r) acc[ct][r] += src[ct * 4 + r];
    }

    float bv = bptr[0];
    float sc[5]; unsigned ab[5];
#pragma unroll
    for (int ct = 0; ct < 5; ++ct) { sc[ct] = scale[ct * 16 + col]; ab[ct] = act[ct]; }

    float contrib = 0.f;
#pragma unroll
    for (int reg = 0; reg < 4; ++reg) {
        int rl = q * 4 + reg;
        int row = rowbase + rl;
        float inv = 1.0f / fmaxf(sqrtf(xn2g[row]), 1e-8f);
        unsigned long long mask = masks[row];
        float v[5]; float lmax = -1e30f;
#pragma unroll
        for (int ct = 0; ct < 5; ++ct) {
            float lg = acc[ct][reg] * sc[ct] * inv + bv;   // w*cos + b
            bool a = (ab[ct] >> col) & 1u;
            v[ct] = a ? lg : -1e30f;
            lmax = fmaxf(lmax, v[ct]);
        }
#pragma unroll
        for (int m = 1; m < 16; m <<= 1) lmax = fmaxf(lmax, __shfl_xor(lmax, m, 16));
        float es = 0.f;
#pragma unroll
        for (int ct = 0; ct < 5; ++ct) es += expf(v[ct] - lmax);
#pragma unroll
        for (int m = 1; m < 16; m <<= 1) es += __shfl_xor(es, m, 16);
        float lse = lmax + logf(es);
        float ps = 0.f;
#pragma unroll
        for (int ct = 0; ct < 5; ++ct) {
            int c = ct * 16 + col;
            bool pos = (c < 64) ? (((mask >> c) & 1ull) != 0ull)
                                : ((c == 64) ? (mask == 0ull) : false);
            ps += pos ? v[ct] : 0.f;
        }
#pragma unroll
        for (int m = 1; m < 16; m <<= 1) ps += __shfl_xor(ps, m, 16);
        float npos = mask ? (float)__popcll(mask) : 1.0f;
        float crow = ps - npos * lse;
        if (col == 0) contrib += crow;
    }
#pragma unroll
    for (int m = 1; m < 64; m <<= 1) contrib += __shfl_xor(contrib, m, 64);
    if (lane == 0) atomicAdd(wsum, contrib);
}

// ---- K4: loss = -sum(logp over positive pairs) / n_pairs ----
__global__ void k4_final(const unsigned* __restrict__ counts,
                         const float* __restrict__ wsum,
                         float* __restrict__ out) {
    if (threadIdx.x == 0 && blockIdx.x == 0) {
        float np = 0.f;
        for (int c = 0; c < NC; ++c) np += (float)counts[c];
        out[0] = -wsum[0] / np;
    }
}

extern "C" void kernel_launch(void* const* d_in, const int* in_sizes, int n_in,
                              void* d_out, int out_size, void* d_ws, size_t ws_size,
                              hipStream_t stream) {
    (void)in_sizes; (void)n_in; (void)out_size;
    const float* x = (const float*)d_in[0];
    const int* label = (const int*)d_in[1];
    const float* w = (const float*)d_in[2];
    const float* b = (const float*)d_in[3];

    char* ws = (char*)d_ws;
    unsigned* counts = (unsigned*)(ws + CNT_B);
    unsigned* act = (unsigned*)(ws + ACT_B);
    float* scale = (float*)(ws + SCALE_B);
    float* wsum = (float*)(ws + WSUM_B);
    unsigned long long* masks = (unsigned long long*)(ws + MASK_B);
    float* xn2g = (float*)(ws + XN2_B);
    unsigned short* lfrag = (unsigned short*)(ws + LFRAG_B);
    unsigned short* bfrag = (unsigned short*)(ws + BFRAG_B);
    unsigned short* xAfrag = (unsigned short*)(ws + XAF_B);
    unsigned short* xcol = (unsigned short*)(ws + XCOL_B);
    float* partial = (float*)(ws + PART_B);

    int kslices = 32;
    while (kslices > 8 && PART_B + (size_t)kslices * SLAB > ws_size) kslices >>= 1;

    hipMemsetAsync(d_ws, 0, ZERO_BYTES, stream);
    hipLaunchKernelGGL(k01_prep, dim3(1024 + 256), dim3(256), 0, stream,
                       x, label, xAfrag, xcol, xn2g, masks, counts, lfrag);
    hipLaunchKernelGGL(k2_sums, dim3(16 * kslices), dim3(256), 0, stream,
                       xcol, lfrag, partial, kslices);
    hipLaunchKernelGGL(k2b_fuse, dim3(CPAD), dim3(256), 0, stream,
                       w, counts, partial, kslices, bfrag, scale, act);
    hipLaunchKernelGGL(k3_loss, dim3(NROWS / 16), dim3(256), 0, stream,
                       xAfrag, bfrag, xn2g, masks, act, scale, b, wsum);
    hipLaunchKernelGGL(k4_final, dim3(1), dim3(64), 0, stream, counts, wsum, (float*)d_out);
}